// Round 8
// baseline (290.928 us; speedup 1.0000x reference)
//
#include <hip/hip_runtime.h>
#include <stdint.h>

// SpikeMLP via exact fixed-point i8 MFMA.
// w -> n = rint(w * 2^42), 5 signed base-256 digits; spikes are {0,1} i8.
// Per-limb i32 MFMA sums exact; i64 Horner exact; f64 scale exact (absmax
// 0.0 in rounds 4/5/6/7 with identical numerics).
// This round: T3/T4 pipeline. 3-deep cyclic LDS B buffers filled by
// global_load_lds, raw s_barrier + counted s_waitcnt vmcnt(13) (never 0 in
// the loop), loop unrolled x2 with ping-pong A-register sets so no aN->aC
// copy forces an early drain. DMA gets ~2 MFMA phases of latency cover.
// A lives in HBM in MFMA-fragment-linear order (AF); A and B use the SAME
// (row,k)->(lane,byte) map so internal k-slot permutations cancel; C/D
// layout decoded at runtime with uniform-byte MFMAs.

typedef int v4i __attribute__((ext_vector_type(4)));
typedef int v16i __attribute__((ext_vector_type(16)));

#define TT 16
constexpr int KD = 2048;
constexpr double SCALE = 4398046511104.0;   // 2^42

#define GLOAD_LDS16(g, s)                                                      \
  __builtin_amdgcn_global_load_lds(                                            \
      (const __attribute__((address_space(1))) uint32_t*)(g),                  \
      (__attribute__((address_space(3))) uint32_t*)(s), 16, 0, 0)

// AF fragment-linear layout: [mtile][ktile(32)][lane][16B],
// lane = (m&31) + 32*((k>>4)&1), byte = k&15.
__device__ __forceinline__ size_t af_addr(int m, int k) {
  return ((size_t)((m >> 5) * 64 + (k >> 5)) << 10)
       + ((size_t)((m & 31) + (((k >> 4) & 1) << 5)) << 4) + (k & 15);
}

// ---------- weight -> 5 signed-digit i8 planes ----------
__global__ __launch_bounds__(256)
void prep_limbs(const float* __restrict__ W, int8_t* __restrict__ dst, int total) {
  const int i4 = (blockIdx.x * 256 + threadIdx.x) * 4;
  if (i4 >= total) return;
  const float4 wv = *reinterpret_cast<const float4*>(W + i4);
  long long n[4];
  n[0] = (long long)rint((double)wv.x * SCALE);
  n[1] = (long long)rint((double)wv.y * SCALE);
  n[2] = (long long)rint((double)wv.z * SCALE);
  n[3] = (long long)rint((double)wv.w * SCALE);
#pragma unroll
  for (int l = 0; l < 5; ++l) {
    char c[4];
#pragma unroll
    for (int e = 0; e < 4; ++e) {
      const int d = (int)((n[e] + 128) & 255) - 128;   // balanced digit
      c[e] = (char)d;
      n[e] = (n[e] - d) >> 8;
    }
    *reinterpret_cast<char4*>(dst + (size_t)l * total + i4) =
        make_char4(c[0], c[1], c[2], c[3]);
  }
}

// ---------- [B][IN][T] f32 -> AF fragment-linear i8 spikes ----------
__global__ __launch_bounds__(256)
void transpose_x_af(const float* __restrict__ in, int8_t* __restrict__ out) {
  const int idx = blockIdx.x * 256 + threadIdx.x;       // (b, i), i fastest
  const float4* src = reinterpret_cast<const float4*>(in) + (size_t)idx * 4;
  float4 v[4];
  v[0] = src[0]; v[1] = src[1]; v[2] = src[2]; v[3] = src[3];
  const float* f = reinterpret_cast<const float*>(v);
  const int b = idx >> 11, i = idx & 2047;
  const size_t base = af_addr(b * TT, i);   // (b*16+t): lane advances by t
#pragma unroll
  for (int t = 0; t < TT; ++t) out[base + (size_t)t * 16] = (int8_t)f[t];
}

static __device__ __forceinline__ v16i zero16() {
  v16i z;
#pragma unroll
  for (int i = 0; i < 16; ++i) z[i] = 0;
  return z;
}

// ---------- fused i8 GEMM (5 limbs) + CLIF scan ----------
// 256 thr / 4 waves; BM=128, BN=64, BK=64. Wave (wy=w>>1, nsub=w&1) owns a
// 64x32 output tile. A frags from AF (global, ping-pong reg prefetch);
// B via global_load_lds into 3-deep fragment-linear LDS, counted vmcnt.
template<int N, bool FINAL>
__global__ __launch_bounds__(256, 2)
void gemm_scan_i8(const int8_t* __restrict__ AF,   // fragment-linear spikes
                  const int8_t* __restrict__ WL,   // [5][N][2048] limbs
                  const float* __restrict__ bias,  // [N]
                  void* __restrict__ outp) {
  __shared__ union SM {
    int8_t b[3][20 * 1024];      // 3-deep B: frag f=l*4+kk*2+ns at f*1024
    double c[4][32 * 33];        // per-wave epilogue C tile (33.8 KB)
  } sm;

  const int tid = threadIdx.x;
  const int lane = tid & 63;
  const int w = tid >> 6;
  const int wy = w >> 1, nsub = w & 1;
  const int m0 = blockIdx.x * 128;
  const int n0 = blockIdx.y * 64;
  const size_t lst = (size_t)N * KD;

  // B DMA jobs: 5 per wave; job j -> frag f = w + 4j; l=f>>2, kk=(f>>1)&1, ns=f&1
  const int8_t* bsrc[5];
  int bdst[5];
#pragma unroll
  for (int j = 0; j < 5; ++j) {
    const int f = w + 4 * j;
    const int l = f >> 2, kk = (f >> 1) & 1, ns = f & 1;
    bsrc[j] = WL + (size_t)l * lst + (size_t)(n0 + ns * 32 + (lane & 31)) * KD
            + kk * 32 + ((lane >> 5) << 4);
    bdst[j] = f * 1024;
  }

  // A fragment pointers: base per mi; ktile offset = (2*t2+kk)*1024
  const int8_t* aP[2];
#pragma unroll
  for (int mi = 0; mi < 2; ++mi)
    aP[mi] = AF + ((size_t)((m0 >> 5) + wy * 2 + mi) << 16) + lane * 16;

  v16i acc[5][2];
#pragma unroll
  for (int l = 0; l < 5; ++l) { acc[l][0] = zero16(); acc[l][1] = zero16(); }

  constexpr int NT2 = KD / 64;   // 32 super-tiles

  // prologue issue order (counted by the loop's vmcnt): DMA(0), A(0), DMA(1)
#pragma unroll
  for (int j = 0; j < 5; ++j) GLOAD_LDS16(bsrc[j], &sm.b[0][bdst[j]]);
  v4i aA[2][2], aB[2][2];
#pragma unroll
  for (int mi = 0; mi < 2; ++mi)
#pragma unroll
    for (int kk = 0; kk < 2; ++kk)
      aA[mi][kk] = *(const v4i*)(aP[mi] + kk * 1024);
#pragma unroll
  for (int j = 0; j < 5; ++j) GLOAD_LDS16(bsrc[j] + 64, &sm.b[1][bdst[j]]);

  int bufc = 0;

  // BODY(t): A(t+1)->ALOAD; wait vmcnt(13) [DMA(t) done, DMA(t+1) still in
  // flight]; barrier; issue DMA(t+2); MFMA(t) on AUSE. Unrolled x2 so the
  // A-register sets ping-pong (no copy -> no early drain of DMA(t+1)).
#define BODY(T, AUSE, ALOAD)                                                   \
  {                                                                            \
    const int t_ = (T);                                                        \
    if (t_ + 1 < NT2) {                                                        \
      _Pragma("unroll")                                                        \
      for (int mi = 0; mi < 2; ++mi)                                           \
        _Pragma("unroll")                                                      \
        for (int kk = 0; kk < 2; ++kk)                                         \
          ALOAD[mi][kk] = *(const v4i*)(aP[mi] + ((t_ + 1) * 2 + kk) * 1024);  \
    }                                                                          \
    if (t_ == NT2 - 1) asm volatile("s_waitcnt vmcnt(4)" ::: "memory");        \
    else               asm volatile("s_waitcnt vmcnt(13)" ::: "memory");       \
    __builtin_amdgcn_s_barrier();                                              \
    if (t_ + 2 < NT2) {                                                        \
      int b2_ = bufc + 2; if (b2_ >= 3) b2_ -= 3;                              \
      _Pragma("unroll")                                                        \
      for (int j = 0; j < 5; ++j)                                              \
        GLOAD_LDS16(bsrc[j] + (size_t)(t_ + 2) * 64, &sm.b[b2_][bdst[j]]);     \
    }                                                                          \
    const int8_t* bb_ = sm.b[bufc];                                            \
    __builtin_amdgcn_s_setprio(1);                                             \
    _Pragma("unroll")                                                          \
    for (int l = 0; l < 5; ++l)                                                \
      _Pragma("unroll")                                                        \
      for (int kk = 0; kk < 2; ++kk) {                                         \
        const v4i bf = *(const v4i*)(bb_ + ((l * 4 + kk * 2 + nsub) << 10)     \
                                         + lane * 16);                         \
        acc[l][0] = __builtin_amdgcn_mfma_i32_32x32x32_i8(AUSE[0][kk], bf,     \
                                                          acc[l][0], 0, 0, 0); \
        acc[l][1] = __builtin_amdgcn_mfma_i32_32x32x32_i8(AUSE[1][kk], bf,     \
                                                          acc[l][1], 0, 0, 0); \
      }                                                                        \
    __builtin_amdgcn_s_setprio(0);                                             \
    ++bufc; if (bufc == 3) bufc = 0;                                           \
  }

  for (int t2 = 0; t2 < NT2; t2 += 2) {
    BODY(t2,     aA, aB);
    BODY(t2 + 1, aB, aA);
  }
#undef BODY

  // ---- decode D layout at runtime (uniform-byte MFMAs, permutation-immune)
  const int rep = (lane & 31) * 0x01010101;
  v4i rowv; rowv[0] = rep; rowv[1] = rep; rowv[2] = rep; rowv[3] = rep;
  v4i onev; onev[0] = 0x01010101; onev[1] = 0x01010101;
            onev[2] = 0x01010101; onev[3] = 0x01010101;
  const v16i drow = __builtin_amdgcn_mfma_i32_32x32x32_i8(rowv, onev, zero16(), 0, 0, 0);
  const v16i dcol = __builtin_amdgcn_mfma_i32_32x32x32_i8(onev, rowv, zero16(), 0, 0, 0);

  // ---- epilogue: 2 passes (mi); combine limbs, scatter f64, CLIF scan ----
  const int col = lane & 31;
  const int bl = lane >> 5;
  double* cw = sm.c[w];
#pragma unroll
  for (int mi = 0; mi < 2; ++mi) {
    __syncthreads();             // full drain; staging dead / prev pass done
#pragma unroll
    for (int i = 0; i < 16; ++i) {
      long long ts = acc[4][mi][i];
      ts = (ts << 8) + acc[3][mi][i];
      ts = (ts << 8) + acc[2][mi][i];
      ts = (ts << 8) + acc[1][mi][i];
      ts = (ts << 8) + acc[0][mi][i];
      cw[(drow[i] >> 5) * 33 + (dcol[i] >> 5)] = (double)ts * 0x1p-42;
    }
    __syncthreads();

    const int gn = n0 + nsub * 32 + col;              // global column
    const int gm = m0 + (wy * 2 + mi) * 32 + bl * 16; // global row of t=0
    const double bj = (double)bias[gn];
    double cc = 0.0, vv = 0.0, ss = 0.0;
    if (!FINAL) {
      int8_t* so = (int8_t*)outp;                     // next layer's AF
      const size_t ab = af_addr(gm, gn);              // +t*16 per step
#pragma unroll
      for (int t = 0; t < TT; ++t) {
        const double x = cw[(bl * 16 + t) * 33 + col] + bj;
        cc = cc * 0.5 + x;                    // NEURON_CDECAY
        vv = vv * 0.75 * (1.0 - ss) + cc;     // NEURON_VDECAY, soft reset
        ss = (vv > 0.5) ? 1.0 : 0.0;          // NEURON_VTH
        so[ab + (size_t)t * 16] = (int8_t)ss;
      }
    } else {
      float tot = 0.0f;
#pragma unroll
      for (int t = 0; t < TT; ++t) {
        const double x = cw[(bl * 16 + t) * 33 + col] + bj;
        cc = cc * 0.5 + x;
        vv = vv * 0.75 * (1.0 - ss) + cc;
        ss = (vv > 0.5) ? 1.0 : 0.0;
        tot += (float)ss;
      }
      ((float*)outp)[(size_t)(gm / TT) * N + gn] = tot * 0.0625f;
    }
  }
}

extern "C" void kernel_launch(void* const* d_in, const int* in_sizes, int n_in,
                              void* d_out, int out_size, void* d_ws, size_t ws_size,
                              hipStream_t stream) {
  const float* X  = (const float*)d_in[0];  // [256][2048][16]
  const float* W0 = (const float*)d_in[1];  // [2048][2048]
  const float* b0 = (const float*)d_in[2];
  const float* W1 = (const float*)d_in[3];  // [2048][2048]
  const float* b1 = (const float*)d_in[4];
  const float* Wo = (const float*)d_in[5];  // [1024][2048]
  const float* bo = (const float*)d_in[6];
  float* out = (float*)d_out;               // [256][1024]

  int8_t* base = (int8_t*)d_ws;
  int8_t* AF0 = base;                                   // 8.39 MB
  int8_t* AF1 = base + (size_t)8388608;                 // 8.39 MB
  int8_t* AF2 = AF0;                                    // reuse after layer 0
  int8_t* L0  = base + (size_t)16777216;                // 21 MB
  int8_t* L1  = base + (size_t)37748736;                // 21 MB
  int8_t* Lo  = base + (size_t)58720256;                // 10.5 MB

  prep_limbs<<<(2048 * 2048 / 4 + 255) / 256, 256, 0, stream>>>(W0, L0, 2048 * 2048);
  prep_limbs<<<(2048 * 2048 / 4 + 255) / 256, 256, 0, stream>>>(W1, L1, 2048 * 2048);
  prep_limbs<<<(1024 * 2048 / 4 + 255) / 256, 256, 0, stream>>>(Wo, Lo, 1024 * 2048);
  transpose_x_af<<<2048, 256, 0, stream>>>(X, AF0);

  gemm_scan_i8<2048, false><<<dim3(32, 32), 256, 0, stream>>>(AF0, L0, b0, AF1);
  gemm_scan_i8<2048, false><<<dim3(32, 32), 256, 0, stream>>>(AF1, L1, b1, AF2);
  gemm_scan_i8<1024, true ><<<dim3(32, 16), 256, 0, stream>>>(AF2, Lo, bo, out);
}

// Round 9
// 236.170 us; speedup vs baseline: 1.2319x; 1.2319x over previous
//
#include <hip/hip_runtime.h>
#include <stdint.h>

// SpikeMLP via exact fixed-point i8 MFMA.
// w -> n = rint(w * 2^42), 5 signed base-256 digits; spikes are {0,1} i8.
// Per-limb i32 MFMA sums exact; i64 Horner exact; f64 scale exact (absmax
// 0.0 in rounds 4/5/6/7/8 with identical numerics).
// This round: BOTH operands live in HBM in MFMA-fragment-linear order.
// A (spikes) in AF; B (weight digit planes) in WF written fragment-linear by
// prep_limbs_wf -> every global_load_lds moves 1024 CONTIGUOUS bytes (16
// fully-used cachelines) instead of a 64-way row-gather. Removes the L2
// request-rate bottleneck diagnosed in r8 (each DMA touched 64 lines).
// A and B use the SAME (row,k)->(lane,byte) map so internal MFMA k-slot
// permutations cancel; C/D layout decoded at runtime with uniform-byte MFMAs.
// Pipeline: 3-deep cyclic LDS B buffers, raw s_barrier + counted
// s_waitcnt vmcnt(13) (never 0 in loop), x2-unrolled ping-pong A regs.

typedef int v4i __attribute__((ext_vector_type(4)));
typedef int v16i __attribute__((ext_vector_type(16)));

#define TT 16
constexpr int KD = 2048;
constexpr double SCALE = 4398046511104.0;   // 2^42

#define GLOAD_LDS16(g, s)                                                      \
  __builtin_amdgcn_global_load_lds(                                            \
      (const __attribute__((address_space(1))) uint32_t*)(g),                  \
      (__attribute__((address_space(3))) uint32_t*)(s), 16, 0, 0)

// Fragment-linear layout (AF and each WF plane):
// addr = [rtile=r>>5][ktile=k>>5][lane=(r&31)+32*((k>>4)&1)][byte=k&15]
__device__ __forceinline__ size_t af_addr(int m, int k) {
  return ((size_t)((m >> 5) * 64 + (k >> 5)) << 10)
       + ((size_t)((m & 31) + (((k >> 4) & 1) << 5)) << 4) + (k & 15);
}

// ---------- weights -> 5 fragment-linear signed-digit i8 planes ----------
// Job g (one 16B output chunk per limb): ntile=g>>12, ktile=(g&4095)>>6,
// lane=g&63 -> row n, k0; dst offset = g*16 in every plane (coalesced).
__global__ __launch_bounds__(256)
void prep_limbs_wf(const float* __restrict__ W, int8_t* __restrict__ dst,
                   int total /* nrows*2048 */) {
  const int g = blockIdx.x * 256 + threadIdx.x;
  const int lane = g & 63;
  const int n = ((g >> 12) << 5) + (lane & 31);
  const int k0 = (((g & 4095) >> 6) << 5) + ((lane >> 5) << 4);
  const float* src = W + (size_t)n * 2048 + k0;
  float4 wv[4];
#pragma unroll
  for (int q = 0; q < 4; ++q) wv[q] = *reinterpret_cast<const float4*>(src + q * 4);
  const float* f = reinterpret_cast<const float*>(wv);
  long long nn[16];
#pragma unroll
  for (int e = 0; e < 16; ++e) nn[e] = (long long)rint((double)f[e] * SCALE);
  const size_t base = (size_t)g * 16;
#pragma unroll
  for (int l = 0; l < 5; ++l) {
    alignas(16) char c[16];
#pragma unroll
    for (int e = 0; e < 16; ++e) {
      const int d = (int)((nn[e] + 128) & 255) - 128;   // balanced digit
      c[e] = (char)d;
      nn[e] = (nn[e] - d) >> 8;
    }
    *reinterpret_cast<v4i*>(dst + (size_t)l * total + base) = *(const v4i*)c;
  }
}

// ---------- [B][IN][T] f32 -> AF fragment-linear i8 spikes ----------
__global__ __launch_bounds__(256)
void transpose_x_af(const float* __restrict__ in, int8_t* __restrict__ out) {
  const int idx = blockIdx.x * 256 + threadIdx.x;       // (b, i), i fastest
  const float4* src = reinterpret_cast<const float4*>(in) + (size_t)idx * 4;
  float4 v[4];
  v[0] = src[0]; v[1] = src[1]; v[2] = src[2]; v[3] = src[3];
  const float* f = reinterpret_cast<const float*>(v);
  const int b = idx >> 11, i = idx & 2047;
  const size_t base = af_addr(b * TT, i);   // (b*16+t): lane advances by t
#pragma unroll
  for (int t = 0; t < TT; ++t) out[base + (size_t)t * 16] = (int8_t)f[t];
}

static __device__ __forceinline__ v16i zero16() {
  v16i z;
#pragma unroll
  for (int i = 0; i < 16; ++i) z[i] = 0;
  return z;
}

// ---------- fused i8 GEMM (5 limbs) + CLIF scan ----------
// 256 thr / 4 waves; BM=128, BN=64, BK=64. Wave (wy=w>>1, nsub=w&1) owns a
// 64x32 output tile. A frags from AF (global, ping-pong reg prefetch);
// B via contiguous global_load_lds into 3-deep LDS, counted vmcnt.
template<int N, bool FINAL>
__global__ __launch_bounds__(256, 2)
void gemm_scan_i8(const int8_t* __restrict__ AF,   // fragment-linear spikes
                  const int8_t* __restrict__ WF,   // [5] fragment-linear planes
                  const float* __restrict__ bias,  // [N]
                  void* __restrict__ outp) {
  __shared__ union SM {
    int8_t b[3][20 * 1024];      // 3-deep B: frag f=l*4+kk*2+ns at f*1024
    double c[4][32 * 33];        // per-wave epilogue C tile (33.8 KB)
  } sm;

  const int tid = threadIdx.x;
  const int lane = tid & 63;
  const int w = tid >> 6;
  const int wy = w >> 1, nsub = w & 1;
  const int m0 = blockIdx.x * 128;
  const int n0 = blockIdx.y * 64;
  const size_t lst = (size_t)N * KD;

  // B DMA jobs: 5 per wave; job j -> frag f = w + 4j; l=f>>2, kk=(f>>1)&1,
  // ns=f&1. Fragment-linear source: 1024 contiguous bytes per instruction.
  // Per super-tile t2 the source advances by 2048 B (2 ktiles).
  const int8_t* bsrc[5];
  int bdst[5];
#pragma unroll
  for (int j = 0; j < 5; ++j) {
    const int f = w + 4 * j;
    const int l = f >> 2, kk = (f >> 1) & 1, ns = f & 1;
    bsrc[j] = WF + (size_t)l * lst
            + ((size_t)(((n0 >> 5) + ns) * (KD >> 5) + kk) << 10) + lane * 16;
    bdst[j] = f * 1024;
  }

  // A fragment pointers: base per mi; ktile offset = (2*t2+kk)*1024
  const int8_t* aP[2];
#pragma unroll
  for (int mi = 0; mi < 2; ++mi)
    aP[mi] = AF + ((size_t)((m0 >> 5) + wy * 2 + mi) << 16) + lane * 16;

  v16i acc[5][2];
#pragma unroll
  for (int l = 0; l < 5; ++l) { acc[l][0] = zero16(); acc[l][1] = zero16(); }

  constexpr int NT2 = KD / 64;   // 32 super-tiles

  // prologue issue order (counted by the loop's vmcnt): DMA(0), A(0), DMA(1)
#pragma unroll
  for (int j = 0; j < 5; ++j) GLOAD_LDS16(bsrc[j], &sm.b[0][bdst[j]]);
  v4i aA[2][2], aB[2][2];
#pragma unroll
  for (int mi = 0; mi < 2; ++mi)
#pragma unroll
    for (int kk = 0; kk < 2; ++kk)
      aA[mi][kk] = *(const v4i*)(aP[mi] + kk * 1024);
#pragma unroll
  for (int j = 0; j < 5; ++j) GLOAD_LDS16(bsrc[j] + 2048, &sm.b[1][bdst[j]]);

  int bufc = 0;

  // BODY(t): A(t+1)->ALOAD; wait vmcnt(13) [DMA(t) done, DMA(t+1) in
  // flight]; barrier; issue DMA(t+2); MFMA(t) on AUSE. Unrolled x2 so the
  // A-register sets ping-pong (no copy -> no early drain of DMA(t+1)).
#define BODY(T, AUSE, ALOAD)                                                   \
  {                                                                            \
    const int t_ = (T);                                                        \
    if (t_ + 1 < NT2) {                                                        \
      _Pragma("unroll")                                                        \
      for (int mi = 0; mi < 2; ++mi)                                           \
        _Pragma("unroll")                                                      \
        for (int kk = 0; kk < 2; ++kk)                                         \
          ALOAD[mi][kk] = *(const v4i*)(aP[mi] + ((t_ + 1) * 2 + kk) * 1024);  \
    }                                                                          \
    if (t_ == NT2 - 1) asm volatile("s_waitcnt vmcnt(4)" ::: "memory");        \
    else               asm volatile("s_waitcnt vmcnt(13)" ::: "memory");       \
    __builtin_amdgcn_s_barrier();                                              \
    if (t_ + 2 < NT2) {                                                        \
      int b2_ = bufc + 2; if (b2_ >= 3) b2_ -= 3;                              \
      _Pragma("unroll")                                                        \
      for (int j = 0; j < 5; ++j)                                              \
        GLOAD_LDS16(bsrc[j] + (size_t)(t_ + 2) * 2048, &sm.b[b2_][bdst[j]]);   \
    }                                                                          \
    const int8_t* bb_ = sm.b[bufc];                                            \
    __builtin_amdgcn_s_setprio(1);                                             \
    _Pragma("unroll")                                                          \
    for (int l = 0; l < 5; ++l)                                                \
      _Pragma("unroll")                                                        \
      for (int kk = 0; kk < 2; ++kk) {                                         \
        const v4i bf = *(const v4i*)(bb_ + ((l * 4 + kk * 2 + nsub) << 10)     \
                                         + lane * 16);                         \
        acc[l][0] = __builtin_amdgcn_mfma_i32_32x32x32_i8(AUSE[0][kk], bf,     \
                                                          acc[l][0], 0, 0, 0); \
        acc[l][1] = __builtin_amdgcn_mfma_i32_32x32x32_i8(AUSE[1][kk], bf,     \
                                                          acc[l][1], 0, 0, 0); \
      }                                                                        \
    __builtin_amdgcn_s_setprio(0);                                             \
    ++bufc; if (bufc == 3) bufc = 0;                                           \
  }

  for (int t2 = 0; t2 < NT2; t2 += 2) {
    BODY(t2,     aA, aB);
    BODY(t2 + 1, aB, aA);
  }
#undef BODY

  // ---- decode D layout at runtime (uniform-byte MFMAs, permutation-immune)
  const int rep = (lane & 31) * 0x01010101;
  v4i rowv; rowv[0] = rep; rowv[1] = rep; rowv[2] = rep; rowv[3] = rep;
  v4i onev; onev[0] = 0x01010101; onev[1] = 0x01010101;
            onev[2] = 0x01010101; onev[3] = 0x01010101;
  const v16i drow = __builtin_amdgcn_mfma_i32_32x32x32_i8(rowv, onev, zero16(), 0, 0, 0);
  const v16i dcol = __builtin_amdgcn_mfma_i32_32x32x32_i8(onev, rowv, zero16(), 0, 0, 0);

  // ---- epilogue: 2 passes (mi); combine limbs, scatter f64, CLIF scan ----
  const int col = lane & 31;
  const int bl = lane >> 5;
  double* cw = sm.c[w];
#pragma unroll
  for (int mi = 0; mi < 2; ++mi) {
    __syncthreads();             // full drain; staging dead / prev pass done
#pragma unroll
    for (int i = 0; i < 16; ++i) {
      long long ts = acc[4][mi][i];
      ts = (ts << 8) + acc[3][mi][i];
      ts = (ts << 8) + acc[2][mi][i];
      ts = (ts << 8) + acc[1][mi][i];
      ts = (ts << 8) + acc[0][mi][i];
      cw[(drow[i] >> 5) * 33 + (dcol[i] >> 5)] = (double)ts * 0x1p-42;
    }
    __syncthreads();

    const int gn = n0 + nsub * 32 + col;              // global column
    const int gm = m0 + (wy * 2 + mi) * 32 + bl * 16; // global row of t=0
    const double bj = (double)bias[gn];
    double cc = 0.0, vv = 0.0, ss = 0.0;
    if (!FINAL) {
      int8_t* so = (int8_t*)outp;                     // next layer's AF
      const size_t ab = af_addr(gm, gn);              // +t*16 per step
#pragma unroll
      for (int t = 0; t < TT; ++t) {
        const double x = cw[(bl * 16 + t) * 33 + col] + bj;
        cc = cc * 0.5 + x;                    // NEURON_CDECAY
        vv = vv * 0.75 * (1.0 - ss) + cc;     // NEURON_VDECAY, soft reset
        ss = (vv > 0.5) ? 1.0 : 0.0;          // NEURON_VTH
        so[ab + (size_t)t * 16] = (int8_t)ss;
      }
    } else {
      float tot = 0.0f;
#pragma unroll
      for (int t = 0; t < TT; ++t) {
        const double x = cw[(bl * 16 + t) * 33 + col] + bj;
        cc = cc * 0.5 + x;
        vv = vv * 0.75 * (1.0 - ss) + cc;
        ss = (vv > 0.5) ? 1.0 : 0.0;
        tot += (float)ss;
      }
      ((float*)outp)[(size_t)(gm / TT) * N + gn] = tot * 0.0625f;
    }
  }
}

extern "C" void kernel_launch(void* const* d_in, const int* in_sizes, int n_in,
                              void* d_out, int out_size, void* d_ws, size_t ws_size,
                              hipStream_t stream) {
  const float* X  = (const float*)d_in[0];  // [256][2048][16]
  const float* W0 = (const float*)d_in[1];  // [2048][2048]
  const float* b0 = (const float*)d_in[2];
  const float* W1 = (const float*)d_in[3];  // [2048][2048]
  const float* b1 = (const float*)d_in[4];
  const float* Wo = (const float*)d_in[5];  // [1024][2048]
  const float* bo = (const float*)d_in[6];
  float* out = (float*)d_out;               // [256][1024]

  int8_t* base = (int8_t*)d_ws;
  int8_t* AF0 = base;                                   // 8.39 MB
  int8_t* AF1 = base + (size_t)8388608;                 // 8.39 MB
  int8_t* AF2 = AF0;                                    // reuse after layer 0
  int8_t* F0  = base + (size_t)16777216;                // 21 MB
  int8_t* F1  = base + (size_t)37748736;                // 21 MB
  int8_t* Fo  = base + (size_t)58720256;                // 10.5 MB

  prep_limbs_wf<<<1024, 256, 0, stream>>>(W0, F0, 2048 * 2048);
  prep_limbs_wf<<<1024, 256, 0, stream>>>(W1, F1, 2048 * 2048);
  prep_limbs_wf<<< 512, 256, 0, stream>>>(Wo, Fo, 1024 * 2048);
  transpose_x_af<<<2048, 256, 0, stream>>>(X, AF0);

  gemm_scan_i8<2048, false><<<dim3(32, 32), 256, 0, stream>>>(AF0, F0, b0, AF1);
  gemm_scan_i8<2048, false><<<dim3(32, 32), 256, 0, stream>>>(AF1, F1, b1, AF2);
  gemm_scan_i8<1024, true ><<<dim3(32, 16), 256, 0, stream>>>(AF2, Fo, bo, out);
}

// Round 10
// 198.307 us; speedup vs baseline: 1.4671x; 1.1909x over previous
//
#include <hip/hip_runtime.h>
#include <stdint.h>

// SpikeMLP via exact fixed-point i8 MFMA.
// w -> n = rint(w * 2^36), 4 signed base-256 digits; spikes are {0,1} i8.
// |n| <= 0.0222*2^36 = 1.52e9 fits 4 balanced digits (range +-2.1e9).
// Per-limb i32 MFMA sums exact (<=2.6e5); i64 Horner exact; f64 scale exact.
// Only deviation vs f64-np reference: 2^-37 weight quantization
// (expected spike flips ~3e-3 across all 21M neuron-steps).
// Both operands fragment-linear in HBM (AF spikes, WF weight planes):
// every global_load_lds moves 1024 contiguous bytes. This round A also goes
// through LDS (removes 2x-redundant per-wave A global reads; L2 path was
// ~90% of per-CU ceiling in r9). 3-deep cyclic LDS buffers, counted
// s_waitcnt vmcnt(6) (never 0 in loop), raw s_barrier.
// A and B use the SAME (row,k)->(lane,byte) map so internal MFMA k-slot
// permutations cancel; C/D layout decoded at runtime with uniform-byte MFMAs.

typedef int v4i __attribute__((ext_vector_type(4)));
typedef int v16i __attribute__((ext_vector_type(16)));

#define TT 16
constexpr int KD = 2048;
constexpr double SCALE = 68719476736.0;   // 2^36

#define GLOAD_LDS16(g, s)                                                      \
  __builtin_amdgcn_global_load_lds(                                            \
      (const __attribute__((address_space(1))) uint32_t*)(g),                  \
      (__attribute__((address_space(3))) uint32_t*)(s), 16, 0, 0)

// Fragment-linear layout (AF and each WF plane):
// addr = [rtile=r>>5][ktile=k>>5][lane=(r&31)+32*((k>>4)&1)][byte=k&15]
__device__ __forceinline__ size_t af_addr(int m, int k) {
  return ((size_t)((m >> 5) * 64 + (k >> 5)) << 10)
       + ((size_t)((m & 31) + (((k >> 4) & 1) << 5)) << 4) + (k & 15);
}

// ---------- weights -> 4 fragment-linear signed-digit i8 planes ----------
__global__ __launch_bounds__(256)
void prep_limbs_wf(const float* __restrict__ W, int8_t* __restrict__ dst,
                   int total /* nrows*2048 */) {
  const int g = blockIdx.x * 256 + threadIdx.x;
  const int lane = g & 63;
  const int n = ((g >> 12) << 5) + (lane & 31);
  const int k0 = (((g & 4095) >> 6) << 5) + ((lane >> 5) << 4);
  const float* src = W + (size_t)n * 2048 + k0;
  float4 wv[4];
#pragma unroll
  for (int q = 0; q < 4; ++q) wv[q] = *reinterpret_cast<const float4*>(src + q * 4);
  const float* f = reinterpret_cast<const float*>(wv);
  long long nn[16];
#pragma unroll
  for (int e = 0; e < 16; ++e) nn[e] = (long long)rint((double)f[e] * SCALE);
  const size_t base = (size_t)g * 16;
#pragma unroll
  for (int l = 0; l < 4; ++l) {
    alignas(16) char c[16];
#pragma unroll
    for (int e = 0; e < 16; ++e) {
      const int d = (int)((nn[e] + 128) & 255) - 128;   // balanced digit
      c[e] = (char)d;
      nn[e] = (nn[e] - d) >> 8;
    }
    *reinterpret_cast<v4i*>(dst + (size_t)l * total + base) = *(const v4i*)c;
  }
}

// ---------- [B][IN][T] f32 -> AF fragment-linear i8 spikes ----------
__global__ __launch_bounds__(256)
void transpose_x_af(const float* __restrict__ in, int8_t* __restrict__ out) {
  const int idx = blockIdx.x * 256 + threadIdx.x;       // (b, i), i fastest
  const float4* src = reinterpret_cast<const float4*>(in) + (size_t)idx * 4;
  float4 v[4];
  v[0] = src[0]; v[1] = src[1]; v[2] = src[2]; v[3] = src[3];
  const float* f = reinterpret_cast<const float*>(v);
  const int b = idx >> 11, i = idx & 2047;
  const size_t base = af_addr(b * TT, i);   // (b*16+t): lane advances by t
#pragma unroll
  for (int t = 0; t < TT; ++t) out[base + (size_t)t * 16] = (int8_t)f[t];
}

static __device__ __forceinline__ v16i zero16() {
  v16i z;
#pragma unroll
  for (int i = 0; i < 16; ++i) z[i] = 0;
  return z;
}

// ---------- fused i8 GEMM (4 limbs) + CLIF scan ----------
// 256 thr / 4 waves; BM=128, BN=64, BK=64. Wave (wy=w>>1, nsub=w&1) owns a
// 64x32 output tile. A AND B staged via contiguous global_load_lds into
// 3-deep LDS buffers; counted vmcnt(6); one barrier per K64.
// Per buffer: A frags fa=mi_l*2+kk at fa*1024 (8 KB), B frags
// f=l*4+kk*2+ns at (8+f)*1024 (16 KB).
template<int N, bool FINAL>
__global__ __launch_bounds__(256, 2)
void gemm_scan_i8(const int8_t* __restrict__ AF,   // fragment-linear spikes
                  const int8_t* __restrict__ WF,   // [4] fragment-linear planes
                  const float* __restrict__ bias,  // [N]
                  void* __restrict__ outp) {
  __shared__ union SM {
    int8_t buf[3][24 * 1024];    // 3-deep {A(8K),B(16K)}            72 KB
    double c[4][32 * 33];        // per-wave epilogue C tile        33.8 KB
  } sm;

  const int tid = threadIdx.x;
  const int lane = tid & 63;
  const int w = tid >> 6;
  const int wy = w >> 1, nsub = w & 1;
  const int m0 = blockIdx.x * 128;
  const int n0 = blockIdx.y * 64;
  const size_t lst = (size_t)N * KD;

  // DMA jobs, 6 per wave: 2 A frags (fa = w, w+4), 4 B frags (f = w+4j).
  // All sources contiguous 1024 B; advance 2048 B per super-tile t2.
  const int8_t* asrc[2];
  int adst[2];
#pragma unroll
  for (int j = 0; j < 2; ++j) {
    const int fa = w + 4 * j;                 // fa = mi_l*2 + kk
    asrc[j] = AF + ((size_t)(((m0 >> 5) + (fa >> 1)) * 64 + (fa & 1)) << 10)
            + lane * 16;
    adst[j] = fa * 1024;
  }
  const int8_t* bsrc[4];
  int bdst[4];
#pragma unroll
  for (int j = 0; j < 4; ++j) {
    const int f = w + 4 * j;                  // f = l*4 + kk*2 + ns
    const int l = f >> 2, kk = (f >> 1) & 1, ns = f & 1;
    bsrc[j] = WF + (size_t)l * lst
            + ((size_t)(((n0 >> 5) + ns) * 64 + kk) << 10) + lane * 16;
    bdst[j] = (8 + f) * 1024;
  }

#define STAGE(T, BUF)                                                          \
  {                                                                            \
    _Pragma("unroll")                                                          \
    for (int j = 0; j < 2; ++j)                                                \
      GLOAD_LDS16(asrc[j] + (size_t)(T) * 2048, &sm.buf[BUF][adst[j]]);        \
    _Pragma("unroll")                                                          \
    for (int j = 0; j < 4; ++j)                                                \
      GLOAD_LDS16(bsrc[j] + (size_t)(T) * 2048, &sm.buf[BUF][bdst[j]]);        \
  }

  v16i acc[4][2];
#pragma unroll
  for (int l = 0; l < 4; ++l) { acc[l][0] = zero16(); acc[l][1] = zero16(); }

  constexpr int NT2 = KD / 64;   // 32 super-tiles

  // prologue: DMA(0) -> buf0, DMA(1) -> buf1  (12 VMEM ops outstanding)
  STAGE(0, 0);
  STAGE(1, 1);

  int bufc = 0;
  for (int t2 = 0; t2 < NT2; ++t2) {
    if (t2 == NT2 - 1) asm volatile("s_waitcnt vmcnt(0)" ::: "memory");
    else               asm volatile("s_waitcnt vmcnt(6)" ::: "memory");
    __builtin_amdgcn_s_barrier();
    if (t2 + 2 < NT2) {
      int b2 = bufc + 2; if (b2 >= 3) b2 -= 3;
      STAGE(t2 + 2, b2);
    }
    const int8_t* bb = sm.buf[bufc];
    v4i afr[2][2];
#pragma unroll
    for (int mi = 0; mi < 2; ++mi)
#pragma unroll
      for (int kk = 0; kk < 2; ++kk)
        afr[mi][kk] = *(const v4i*)(bb + ((((wy * 2 + mi) << 1) | kk) << 10)
                                       + lane * 16);
    __builtin_amdgcn_s_setprio(1);
#pragma unroll
    for (int l = 0; l < 4; ++l)
#pragma unroll
      for (int kk = 0; kk < 2; ++kk) {
        const v4i bf = *(const v4i*)(bb + ((8 + ((l << 2) | (kk << 1) | nsub)) << 10)
                                        + lane * 16);
        acc[l][0] = __builtin_amdgcn_mfma_i32_32x32x32_i8(afr[0][kk], bf, acc[l][0], 0, 0, 0);
        acc[l][1] = __builtin_amdgcn_mfma_i32_32x32x32_i8(afr[1][kk], bf, acc[l][1], 0, 0, 0);
      }
    __builtin_amdgcn_s_setprio(0);
    ++bufc; if (bufc == 3) bufc = 0;
  }
#undef STAGE

  // ---- decode D layout at runtime (uniform-byte MFMAs, permutation-immune)
  const int rep = (lane & 31) * 0x01010101;
  v4i rowv; rowv[0] = rep; rowv[1] = rep; rowv[2] = rep; rowv[3] = rep;
  v4i onev; onev[0] = 0x01010101; onev[1] = 0x01010101;
            onev[2] = 0x01010101; onev[3] = 0x01010101;
  const v16i drow = __builtin_amdgcn_mfma_i32_32x32x32_i8(rowv, onev, zero16(), 0, 0, 0);
  const v16i dcol = __builtin_amdgcn_mfma_i32_32x32x32_i8(onev, rowv, zero16(), 0, 0, 0);

  // ---- epilogue: 2 passes (mi); combine limbs, scatter f64, CLIF scan ----
  const int col = lane & 31;
  const int bl = lane >> 5;
  double* cw = sm.c[w];
#pragma unroll
  for (int mi = 0; mi < 2; ++mi) {
    __syncthreads();             // full drain; staging dead / prev pass done
#pragma unroll
    for (int i = 0; i < 16; ++i) {
      long long ts = acc[3][mi][i];
      ts = (ts << 8) + acc[2][mi][i];
      ts = (ts << 8) + acc[1][mi][i];
      ts = (ts << 8) + acc[0][mi][i];
      cw[(drow[i] >> 5) * 33 + (dcol[i] >> 5)] = (double)ts * 0x1p-36;
    }
    __syncthreads();

    const int gn = n0 + nsub * 32 + col;              // global column
    const int gm = m0 + (wy * 2 + mi) * 32 + bl * 16; // global row of t=0
    const double bj = (double)bias[gn];
    double cc = 0.0, vv = 0.0, ss = 0.0;
    if (!FINAL) {
      int8_t* so = (int8_t*)outp;                     // next layer's AF
      const size_t ab = af_addr(gm, gn);              // +t*16 per step
#pragma unroll
      for (int t = 0; t < TT; ++t) {
        const double x = cw[(bl * 16 + t) * 33 + col] + bj;
        cc = cc * 0.5 + x;                    // NEURON_CDECAY
        vv = vv * 0.75 * (1.0 - ss) + cc;     // NEURON_VDECAY, soft reset
        ss = (vv > 0.5) ? 1.0 : 0.0;          // NEURON_VTH
        so[ab + (size_t)t * 16] = (int8_t)ss;
      }
    } else {
      float tot = 0.0f;
#pragma unroll
      for (int t = 0; t < TT; ++t) {
        const double x = cw[(bl * 16 + t) * 33 + col] + bj;
        cc = cc * 0.5 + x;
        vv = vv * 0.75 * (1.0 - ss) + cc;
        ss = (vv > 0.5) ? 1.0 : 0.0;
        tot += (float)ss;
      }
      ((float*)outp)[(size_t)(gm / TT) * N + gn] = tot * 0.0625f;
    }
  }
}

extern "C" void kernel_launch(void* const* d_in, const int* in_sizes, int n_in,
                              void* d_out, int out_size, void* d_ws, size_t ws_size,
                              hipStream_t stream) {
  const float* X  = (const float*)d_in[0];  // [256][2048][16]
  const float* W0 = (const float*)d_in[1];  // [2048][2048]
  const float* b0 = (const float*)d_in[2];
  const float* W1 = (const float*)d_in[3];  // [2048][2048]
  const float* b1 = (const float*)d_in[4];
  const float* Wo = (const float*)d_in[5];  // [1024][2048]
  const float* bo = (const float*)d_in[6];
  float* out = (float*)d_out;               // [256][1024]

  int8_t* base = (int8_t*)d_ws;
  int8_t* AF0 = base;                                   // 8.39 MB
  int8_t* AF1 = base + (size_t)8388608;                 // 8.39 MB
  int8_t* AF2 = AF0;                                    // reuse after layer 0
  int8_t* F0  = base + (size_t)16777216;                // 4x4 MB = 16.8 MB
  int8_t* F1  = base + (size_t)33554432;                // 16.8 MB
  int8_t* Fo  = base + (size_t)50331648;                // 8.39 MB

  prep_limbs_wf<<<1024, 256, 0, stream>>>(W0, F0, 2048 * 2048);
  prep_limbs_wf<<<1024, 256, 0, stream>>>(W1, F1, 2048 * 2048);
  prep_limbs_wf<<< 512, 256, 0, stream>>>(Wo, Fo, 1024 * 2048);
  transpose_x_af<<<2048, 256, 0, stream>>>(X, AF0);

  gemm_scan_i8<2048, false><<<dim3(32, 32), 256, 0, stream>>>(AF0, F0, b0, AF1);
  gemm_scan_i8<2048, false><<<dim3(32, 32), 256, 0, stream>>>(AF1, F1, b1, AF2);
  gemm_scan_i8<1024, true ><<<dim3(32, 16), 256, 0, stream>>>(AF2, Fo, bo, out);
}

// Round 11
// 192.908 us; speedup vs baseline: 1.5081x; 1.0280x over previous
//
#include <hip/hip_runtime.h>
#include <stdint.h>

// SpikeMLP via exact fixed-point i8 MFMA.
// w -> n = rint(w * 2^36), 4 signed base-256 digits; spikes are {0,1} i8.
// Per-limb i32 MFMA sums exact (<=2.6e5); i64 Horner exact; f64 scale exact.
// Only deviation vs f64-np reference: 2^-37 weight quantization (expected
// spike flips ~1e-3 over all 21M neuron-steps). absmax 0.0 in r10.
// Both operands fragment-linear in HBM (AF spikes, WF planes): every
// global_load_lds moves 1024 contiguous bytes into 3-deep LDS buffers,
// counted s_waitcnt vmcnt(6) (never 0 in loop), raw s_barrier.
// R11: (1) XCD-chunked + 8x8-panel block swizzle (per-XCD L2 working set
// ~6 MB instead of ~16 MB -> kill the 3x L2-miss amplification seen in
// FETCH_SIZE); (2) 2-phase K-step: barrier-gated pure-MFMA clusters with
// lgkmcnt(0)+setprio (T3/T5 structure).
// A and B use the SAME (row,k)->(lane,byte) map so internal MFMA k-slot
// permutations cancel; C/D layout decoded at runtime with uniform-byte MFMAs.

typedef int v4i __attribute__((ext_vector_type(4)));
typedef int v16i __attribute__((ext_vector_type(16)));

#define TT 16
constexpr int KD = 2048;
constexpr double SCALE = 68719476736.0;   // 2^36

#define GLOAD_LDS16(g, s)                                                      \
  __builtin_amdgcn_global_load_lds(                                            \
      (const __attribute__((address_space(1))) uint32_t*)(g),                  \
      (__attribute__((address_space(3))) uint32_t*)(s), 16, 0, 0)

// Fragment-linear layout (AF and each WF plane):
// addr = [rtile=r>>5][ktile=k>>5][lane=(r&31)+32*((k>>4)&1)][byte=k&15]
__device__ __forceinline__ size_t af_addr(int m, int k) {
  return ((size_t)((m >> 5) * 64 + (k >> 5)) << 10)
       + ((size_t)((m & 31) + (((k >> 4) & 1) << 5)) << 4) + (k & 15);
}

// ---------- weights -> 4 fragment-linear signed-digit i8 planes ----------
__global__ __launch_bounds__(256)
void prep_limbs_wf(const float* __restrict__ W, int8_t* __restrict__ dst,
                   int total /* nrows*2048 */) {
  const int g = blockIdx.x * 256 + threadIdx.x;
  const int lane = g & 63;
  const int n = ((g >> 12) << 5) + (lane & 31);
  const int k0 = (((g & 4095) >> 6) << 5) + ((lane >> 5) << 4);
  const float* src = W + (size_t)n * 2048 + k0;
  float4 wv[4];
#pragma unroll
  for (int q = 0; q < 4; ++q) wv[q] = *reinterpret_cast<const float4*>(src + q * 4);
  const float* f = reinterpret_cast<const float*>(wv);
  long long nn[16];
#pragma unroll
  for (int e = 0; e < 16; ++e) nn[e] = (long long)rint((double)f[e] * SCALE);
  const size_t base = (size_t)g * 16;
#pragma unroll
  for (int l = 0; l < 4; ++l) {
    alignas(16) char c[16];
#pragma unroll
    for (int e = 0; e < 16; ++e) {
      const int d = (int)((nn[e] + 128) & 255) - 128;   // balanced digit
      c[e] = (char)d;
      nn[e] = (nn[e] - d) >> 8;
    }
    *reinterpret_cast<v4i*>(dst + (size_t)l * total + base) = *(const v4i*)c;
  }
}

// ---------- [B][IN][T] f32 -> AF fragment-linear i8 spikes ----------
__global__ __launch_bounds__(256)
void transpose_x_af(const float* __restrict__ in, int8_t* __restrict__ out) {
  const int idx = blockIdx.x * 256 + threadIdx.x;       // (b, i), i fastest
  const float4* src = reinterpret_cast<const float4*>(in) + (size_t)idx * 4;
  float4 v[4];
  v[0] = src[0]; v[1] = src[1]; v[2] = src[2]; v[3] = src[3];
  const float* f = reinterpret_cast<const float*>(v);
  const int b = idx >> 11, i = idx & 2047;
  const size_t base = af_addr(b * TT, i);   // (b*16+t): lane advances by t
#pragma unroll
  for (int t = 0; t < TT; ++t) out[base + (size_t)t * 16] = (int8_t)f[t];
}

static __device__ __forceinline__ v16i zero16() {
  v16i z;
#pragma unroll
  for (int i = 0; i < 16; ++i) z[i] = 0;
  return z;
}

// ---------- fused i8 GEMM (4 limbs) + CLIF scan ----------
// 256 thr / 4 waves; BM=128, BN=64, BK=64. Wave (wy=w>>1, nsub=w&1) owns a
// 64x32 output tile. 1-D grid, XCD-chunked + 8x8-panel swizzle.
template<int N, bool FINAL>
__global__ __launch_bounds__(256, 2)
void gemm_scan_i8(const int8_t* __restrict__ AF,   // fragment-linear spikes
                  const int8_t* __restrict__ WF,   // [4] fragment-linear planes
                  const float* __restrict__ bias,  // [N]
                  void* __restrict__ outp) {
  __shared__ union SM {
    int8_t buf[3][24 * 1024];    // 3-deep {A(8K),B(16K)}            72 KB
    double c[4][32 * 33];        // per-wave epilogue C tile        33.8 KB
  } sm;

  const int tid = threadIdx.x;
  const int lane = tid & 63;
  const int w = tid >> 6;
  const int wy = w >> 1, nsub = w & 1;

  // ---- XCD-chunked bijective swizzle + 8x8 tile panels ----
  constexpr int NN = N / 64;               // n-tiles (32 or 16)
  constexpr int NWG = 32 * NN;             // m-tiles(32) x n-tiles; %8 == 0
  const int h = blockIdx.x;
  const int wk = (h & 7) * (NWG >> 3) + (h >> 3);   // chunk per XCD
  const int panel = wk >> 6;               // 64-block panels = 8m x 8n
  const int within = wk & 63;
  const int mt = (panel & 3) * 8 + (within & 7);    // 32/8 = 4 pm groups
  const int nt = (panel >> 2) * 8 + (within >> 3);
  const int m0 = mt * 128;
  const int n0 = nt * 64;
  const size_t lst = (size_t)N * KD;

  // DMA jobs, 6 per wave: 2 A frags (fa = w, w+4), 4 B frags (f = w+4j).
  // All sources contiguous 1024 B; advance 2048 B per super-tile t2.
  const int8_t* asrc[2];
  int adst[2];
#pragma unroll
  for (int j = 0; j < 2; ++j) {
    const int fa = w + 4 * j;                 // fa = mi_l*2 + kk
    asrc[j] = AF + ((size_t)(((m0 >> 5) + (fa >> 1)) * 64 + (fa & 1)) << 10)
            + lane * 16;
    adst[j] = fa * 1024;
  }
  const int8_t* bsrc[4];
  int bdst[4];
#pragma unroll
  for (int j = 0; j < 4; ++j) {
    const int f = w + 4 * j;                  // f = l*4 + kk*2 + ns
    const int l = f >> 2, kk = (f >> 1) & 1, ns = f & 1;
    bsrc[j] = WF + (size_t)l * lst
            + ((size_t)(((n0 >> 5) + ns) * 64 + kk) << 10) + lane * 16;
    bdst[j] = (8 + f) * 1024;
  }

#define STAGE(T, BUF)                                                          \
  {                                                                            \
    _Pragma("unroll")                                                          \
    for (int j = 0; j < 2; ++j)                                                \
      GLOAD_LDS16(asrc[j] + (size_t)(T) * 2048, &sm.buf[BUF][adst[j]]);        \
    _Pragma("unroll")                                                          \
    for (int j = 0; j < 4; ++j)                                                \
      GLOAD_LDS16(bsrc[j] + (size_t)(T) * 2048, &sm.buf[BUF][bdst[j]]);        \
  }

  v16i acc[4][2];
#pragma unroll
  for (int l = 0; l < 4; ++l) { acc[l][0] = zero16(); acc[l][1] = zero16(); }

  constexpr int NT2 = KD / 64;   // 32 super-tiles

  // prologue: DMA(0) -> buf0, DMA(1) -> buf1  (12 VMEM ops outstanding)
  STAGE(0, 0);
  STAGE(1, 1);

  int bufc = 0;
  for (int t2 = 0; t2 < NT2; ++t2) {
    if (t2 == NT2 - 1) asm volatile("s_waitcnt vmcnt(0)" ::: "memory");
    else               asm volatile("s_waitcnt vmcnt(6)" ::: "memory");
    __builtin_amdgcn_s_barrier();            // buf(t2) ready for all waves
    if (t2 + 2 < NT2) {
      int b2 = bufc + 2; if (b2 >= 3) b2 -= 3;
      STAGE(t2 + 2, b2);
    }
    const int8_t* bb = sm.buf[bufc];

    // ---- phase 0: reads (A x4, B limbs 0-1 x4), gate, pure-MFMA cluster
    v4i afr[2][2], b01[2][2];
#pragma unroll
    for (int mi = 0; mi < 2; ++mi)
#pragma unroll
      for (int kk = 0; kk < 2; ++kk)
        afr[mi][kk] = *(const v4i*)(bb + ((((wy * 2 + mi) << 1) | kk) << 10)
                                       + lane * 16);
#pragma unroll
    for (int l = 0; l < 2; ++l)
#pragma unroll
      for (int kk = 0; kk < 2; ++kk)
        b01[l][kk] = *(const v4i*)(bb + ((8 + ((l << 2) | (kk << 1) | nsub)) << 10)
                                      + lane * 16);
    __builtin_amdgcn_s_barrier();
    asm volatile("s_waitcnt lgkmcnt(0)" ::: "memory");
    __builtin_amdgcn_sched_barrier(0);       // rule #18: pin MFMA after wait
    __builtin_amdgcn_s_setprio(1);
#pragma unroll
    for (int l = 0; l < 2; ++l)
#pragma unroll
      for (int kk = 0; kk < 2; ++kk) {
        acc[l][0] = __builtin_amdgcn_mfma_i32_32x32x32_i8(afr[0][kk], b01[l][kk], acc[l][0], 0, 0, 0);
        acc[l][1] = __builtin_amdgcn_mfma_i32_32x32x32_i8(afr[1][kk], b01[l][kk], acc[l][1], 0, 0, 0);
      }
    __builtin_amdgcn_s_setprio(0);

    // ---- phase 1: reads (B limbs 2-3 x4), gate, pure-MFMA cluster
    v4i b23[2][2];
#pragma unroll
    for (int l = 0; l < 2; ++l)
#pragma unroll
      for (int kk = 0; kk < 2; ++kk)
        b23[l][kk] = *(const v4i*)(bb + ((8 + (((l + 2) << 2) | (kk << 1) | nsub)) << 10)
                                      + lane * 16);
    __builtin_amdgcn_s_barrier();
    asm volatile("s_waitcnt lgkmcnt(0)" ::: "memory");
    __builtin_amdgcn_sched_barrier(0);
    __builtin_amdgcn_s_setprio(1);
#pragma unroll
    for (int l = 0; l < 2; ++l)
#pragma unroll
      for (int kk = 0; kk < 2; ++kk) {
        acc[l + 2][0] = __builtin_amdgcn_mfma_i32_32x32x32_i8(afr[0][kk], b23[l][kk], acc[l + 2][0], 0, 0, 0);
        acc[l + 2][1] = __builtin_amdgcn_mfma_i32_32x32x32_i8(afr[1][kk], b23[l][kk], acc[l + 2][1], 0, 0, 0);
      }
    __builtin_amdgcn_s_setprio(0);

    ++bufc; if (bufc == 3) bufc = 0;
  }
#undef STAGE

  // ---- decode D layout at runtime (uniform-byte MFMAs, permutation-immune)
  const int rep = (lane & 31) * 0x01010101;
  v4i rowv; rowv[0] = rep; rowv[1] = rep; rowv[2] = rep; rowv[3] = rep;
  v4i onev; onev[0] = 0x01010101; onev[1] = 0x01010101;
            onev[2] = 0x01010101; onev[3] = 0x01010101;
  const v16i drow = __builtin_amdgcn_mfma_i32_32x32x32_i8(rowv, onev, zero16(), 0, 0, 0);
  const v16i dcol = __builtin_amdgcn_mfma_i32_32x32x32_i8(onev, rowv, zero16(), 0, 0, 0);

  // ---- epilogue: 2 passes (mi); combine limbs, scatter f64, CLIF scan ----
  const int col = lane & 31;
  const int bl = lane >> 5;
  double* cw = sm.c[w];
#pragma unroll
  for (int mi = 0; mi < 2; ++mi) {
    __syncthreads();             // full drain; staging dead / prev pass done
#pragma unroll
    for (int i = 0; i < 16; ++i) {
      long long ts = acc[3][mi][i];
      ts = (ts << 8) + acc[2][mi][i];
      ts = (ts << 8) + acc[1][mi][i];
      ts = (ts << 8) + acc[0][mi][i];
      cw[(drow[i] >> 5) * 33 + (dcol[i] >> 5)] = (double)ts * 0x1p-36;
    }
    __syncthreads();

    const int gn = n0 + nsub * 32 + col;              // global column
    const int gm = m0 + (wy * 2 + mi) * 32 + bl * 16; // global row of t=0
    const double bj = (double)bias[gn];
    double cc = 0.0, vv = 0.0, ss = 0.0;
    if (!FINAL) {
      int8_t* so = (int8_t*)outp;                     // next layer's AF
      const size_t ab = af_addr(gm, gn);              // +t*16 per step
#pragma unroll
      for (int t = 0; t < TT; ++t) {
        const double x = cw[(bl * 16 + t) * 33 + col] + bj;
        cc = cc * 0.5 + x;                    // NEURON_CDECAY
        vv = vv * 0.75 * (1.0 - ss) + cc;     // NEURON_VDECAY, soft reset
        ss = (vv > 0.5) ? 1.0 : 0.0;          // NEURON_VTH
        so[ab + (size_t)t * 16] = (int8_t)ss;
      }
    } else {
      float tot = 0.0f;
#pragma unroll
      for (int t = 0; t < TT; ++t) {
        const double x = cw[(bl * 16 + t) * 33 + col] + bj;
        cc = cc * 0.5 + x;
        vv = vv * 0.75 * (1.0 - ss) + cc;
        ss = (vv > 0.5) ? 1.0 : 0.0;
        tot += (float)ss;
      }
      ((float*)outp)[(size_t)(gm / TT) * N + gn] = tot * 0.0625f;
    }
  }
}

extern "C" void kernel_launch(void* const* d_in, const int* in_sizes, int n_in,
                              void* d_out, int out_size, void* d_ws, size_t ws_size,
                              hipStream_t stream) {
  const float* X  = (const float*)d_in[0];  // [256][2048][16]
  const float* W0 = (const float*)d_in[1];  // [2048][2048]
  const float* b0 = (const float*)d_in[2];
  const float* W1 = (const float*)d_in[3];  // [2048][2048]
  const float* b1 = (const float*)d_in[4];
  const float* Wo = (const float*)d_in[5];  // [1024][2048]
  const float* bo = (const float*)d_in[6];
  float* out = (float*)d_out;               // [256][1024]

  int8_t* base = (int8_t*)d_ws;
  int8_t* AF0 = base;                                   // 8.39 MB
  int8_t* AF1 = base + (size_t)8388608;                 // 8.39 MB
  int8_t* AF2 = AF0;                                    // reuse after layer 0
  int8_t* F0  = base + (size_t)16777216;                // 4x4 MB = 16.8 MB
  int8_t* F1  = base + (size_t)33554432;                // 16.8 MB
  int8_t* Fo  = base + (size_t)50331648;                // 8.39 MB

  prep_limbs_wf<<<1024, 256, 0, stream>>>(W0, F0, 2048 * 2048);
  prep_limbs_wf<<<1024, 256, 0, stream>>>(W1, F1, 2048 * 2048);
  prep_limbs_wf<<< 512, 256, 0, stream>>>(Wo, Fo, 1024 * 2048);
  transpose_x_af<<<2048, 256, 0, stream>>>(X, AF0);

  gemm_scan_i8<2048, false><<<1024, 256, 0, stream>>>(AF0, F0, b0, AF1);
  gemm_scan_i8<2048, false><<<1024, 256, 0, stream>>>(AF1, F1, b1, AF2);
  gemm_scan_i8<1024, true ><<< 512, 256, 0, stream>>>(AF2, Fo, bo, out);
}

// Round 12
// 186.352 us; speedup vs baseline: 1.5612x; 1.0352x over previous
//
#include <hip/hip_runtime.h>
#include <stdint.h>

// SpikeMLP via exact fixed-point i8 MFMA.
// w -> n = rint(w * 2^36), 4 signed base-256 digits; spikes are {0,1} i8.
// Per-limb i32 MFMA sums exact (<=2.6e5); i64 Horner exact; f64 scale exact.
// Only deviation vs f64-np reference: 2^-37 weight quantization. absmax 0.0
// in r10/r11 with identical numerics.
// Both operands fragment-linear in HBM; global_load_lds moves 1024
// contiguous bytes into 3-deep LDS buffers; counted s_waitcnt vmcnt(6);
// XCD-chunked bijective swizzle + 8x8 panels (r11: FETCH 74->49 MB).
// R12: 4-phase K-step (T3): per phase {issue 1-2 DMA(t+2) ; 2-6 ds_read ;
// s_barrier ; lgkmcnt(0)+sched_barrier ; setprio-wrapped 4-MFMA cluster}.
// Fine-grained phase gates let the 2 co-resident blocks' MFMA clusters fill
// each other's read/barrier gaps (catalog T3/T5 mechanism).
// A and B use the SAME (row,k)->(lane,byte) map so internal MFMA k-slot
// permutations cancel; C/D layout decoded at runtime with uniform-byte MFMAs.

typedef int v4i __attribute__((ext_vector_type(4)));
typedef int v16i __attribute__((ext_vector_type(16)));

#define TT 16
constexpr int KD = 2048;
constexpr double SCALE = 68719476736.0;   // 2^36

#define GLOAD_LDS16(g, s)                                                      \
  __builtin_amdgcn_global_load_lds(                                            \
      (const __attribute__((address_space(1))) uint32_t*)(g),                  \
      (__attribute__((address_space(3))) uint32_t*)(s), 16, 0, 0)

// Fragment-linear layout (AF and each WF plane):
// addr = [rtile=r>>5][ktile=k>>5][lane=(r&31)+32*((k>>4)&1)][byte=k&15]
__device__ __forceinline__ size_t af_addr(int m, int k) {
  return ((size_t)((m >> 5) * 64 + (k >> 5)) << 10)
       + ((size_t)((m & 31) + (((k >> 4) & 1) << 5)) << 4) + (k & 15);
}

// ---------- all weights -> 4 fragment-linear signed-digit i8 planes ----------
// One fused dispatch: blocks [0,1024) W0, [1024,2048) W1, [2048,2560) Wo.
__global__ __launch_bounds__(256)
void prep_limbs_all(const float* __restrict__ W0, const float* __restrict__ W1,
                    const float* __restrict__ Wo, int8_t* __restrict__ F0,
                    int8_t* __restrict__ F1, int8_t* __restrict__ Fo) {
  int blk = blockIdx.x;
  const float* W;
  int8_t* dst;
  int total;
  if (blk < 1024)      { W = W0; dst = F0; total = 2048 * 2048; }
  else if (blk < 2048) { W = W1; dst = F1; total = 2048 * 2048; blk -= 1024; }
  else                 { W = Wo; dst = Fo; total = 1024 * 2048; blk -= 2048; }
  const int g = blk * 256 + threadIdx.x;
  const int lane = g & 63;
  const int n = ((g >> 12) << 5) + (lane & 31);
  const int k0 = (((g & 4095) >> 6) << 5) + ((lane >> 5) << 4);
  const float* src = W + (size_t)n * 2048 + k0;
  float4 wv[4];
#pragma unroll
  for (int q = 0; q < 4; ++q) wv[q] = *reinterpret_cast<const float4*>(src + q * 4);
  const float* f = reinterpret_cast<const float*>(wv);
  long long nn[16];
#pragma unroll
  for (int e = 0; e < 16; ++e) nn[e] = (long long)rint((double)f[e] * SCALE);
  const size_t base = (size_t)g * 16;
#pragma unroll
  for (int l = 0; l < 4; ++l) {
    alignas(16) char c[16];
#pragma unroll
    for (int e = 0; e < 16; ++e) {
      const int d = (int)((nn[e] + 128) & 255) - 128;   // balanced digit
      c[e] = (char)d;
      nn[e] = (nn[e] - d) >> 8;
    }
    *reinterpret_cast<v4i*>(dst + (size_t)l * total + base) = *(const v4i*)c;
  }
}

// ---------- [B][IN][T] f32 -> AF fragment-linear i8 spikes ----------
__global__ __launch_bounds__(256)
void transpose_x_af(const float* __restrict__ in, int8_t* __restrict__ out) {
  const int idx = blockIdx.x * 256 + threadIdx.x;       // (b, i), i fastest
  const float4* src = reinterpret_cast<const float4*>(in) + (size_t)idx * 4;
  float4 v[4];
  v[0] = src[0]; v[1] = src[1]; v[2] = src[2]; v[3] = src[3];
  const float* f = reinterpret_cast<const float*>(v);
  const int b = idx >> 11, i = idx & 2047;
  const size_t base = af_addr(b * TT, i);   // (b*16+t): lane advances by t
#pragma unroll
  for (int t = 0; t < TT; ++t) out[base + (size_t)t * 16] = (int8_t)f[t];
}

static __device__ __forceinline__ v16i zero16() {
  v16i z;
#pragma unroll
  for (int i = 0; i < 16; ++i) z[i] = 0;
  return z;
}

// ---------- fused i8 GEMM (4 limbs) + CLIF scan, 4-phase K-step ----------
// 256 thr / 4 waves; BM=128, BN=64, BK=64. Wave (wy=w>>1, nsub=w&1) owns a
// 64x32 output tile. 1-D grid, XCD-chunked + 8x8-panel swizzle.
template<int N, bool FINAL>
__global__ __launch_bounds__(256, 2)
void gemm_scan_i8(const int8_t* __restrict__ AF,   // fragment-linear spikes
                  const int8_t* __restrict__ WF,   // [4] fragment-linear planes
                  const float* __restrict__ bias,  // [N]
                  void* __restrict__ outp) {
  __shared__ union SM {
    int8_t buf[3][24 * 1024];    // 3-deep {A(8K),B(16K)}            72 KB
    double c[4][32 * 33];        // per-wave epilogue C tile        33.8 KB
  } sm;

  const int tid = threadIdx.x;
  const int lane = tid & 63;
  const int w = tid >> 6;
  const int wy = w >> 1, nsub = w & 1;

  // ---- XCD-chunked bijective swizzle + 8x8 tile panels ----
  constexpr int NN = N / 64;               // n-tiles (32 or 16)
  constexpr int NWG = 32 * NN;             // m-tiles(32) x n-tiles; %8 == 0
  const int h = blockIdx.x;
  const int wk = (h & 7) * (NWG >> 3) + (h >> 3);   // chunk per XCD
  const int panel = wk >> 6;               // 64-block panels = 8m x 8n
  const int within = wk & 63;
  const int mt = (panel & 3) * 8 + (within & 7);
  const int nt = (panel >> 2) * 8 + (within >> 3);
  const int m0 = mt * 128;
  const int n0 = nt * 64;
  const size_t lst = (size_t)N * KD;

  // DMA jobs, 6 per wave: 2 A frags (fa = w, w+4), 4 B frags (f = w+4j).
  const int8_t* asrc[2];
  int adst[2];
#pragma unroll
  for (int j = 0; j < 2; ++j) {
    const int fa = w + 4 * j;                 // fa = mi_l*2 + kk
    asrc[j] = AF + ((size_t)(((m0 >> 5) + (fa >> 1)) * 64 + (fa & 1)) << 10)
            + lane * 16;
    adst[j] = fa * 1024;
  }
  const int8_t* bsrc[4];
  int bdst[4];
#pragma unroll
  for (int j = 0; j < 4; ++j) {
    const int f = w + 4 * j;                  // f = l*4 + kk*2 + ns
    const int l = f >> 2, kk = (f >> 1) & 1, ns = f & 1;
    bsrc[j] = WF + (size_t)l * lst
            + ((size_t)(((n0 >> 5) + ns) * 64 + kk) << 10) + lane * 16;
    bdst[j] = (8 + f) * 1024;
  }

  v16i acc[4][2];
#pragma unroll
  for (int l = 0; l < 4; ++l) { acc[l][0] = zero16(); acc[l][1] = zero16(); }

  constexpr int NT2 = KD / 64;   // 32 super-tiles

  // prologue: DMA(0) -> buf0, DMA(1) -> buf1  (12 VMEM ops outstanding)
#pragma unroll
  for (int j = 0; j < 2; ++j) GLOAD_LDS16(asrc[j], &sm.buf[0][adst[j]]);
#pragma unroll
  for (int j = 0; j < 4; ++j) GLOAD_LDS16(bsrc[j], &sm.buf[0][bdst[j]]);
#pragma unroll
  for (int j = 0; j < 2; ++j) GLOAD_LDS16(asrc[j] + 2048, &sm.buf[1][adst[j]]);
#pragma unroll
  for (int j = 0; j < 4; ++j) GLOAD_LDS16(bsrc[j] + 2048, &sm.buf[1][bdst[j]]);

#define GATE()                                                                 \
  __builtin_amdgcn_s_barrier();                                                \
  asm volatile("s_waitcnt lgkmcnt(0)" ::: "memory");                           \
  __builtin_amdgcn_sched_barrier(0)

#define MFMA4(L, BF)                                                           \
  __builtin_amdgcn_s_setprio(1);                                               \
  acc[L][0] = __builtin_amdgcn_mfma_i32_32x32x32_i8(afr[0][0], BF[0], acc[L][0], 0, 0, 0); \
  acc[L][1] = __builtin_amdgcn_mfma_i32_32x32x32_i8(afr[1][0], BF[0], acc[L][1], 0, 0, 0); \
  acc[L][0] = __builtin_amdgcn_mfma_i32_32x32x32_i8(afr[0][1], BF[1], acc[L][0], 0, 0, 0); \
  acc[L][1] = __builtin_amdgcn_mfma_i32_32x32x32_i8(afr[1][1], BF[1], acc[L][1], 0, 0, 0); \
  __builtin_amdgcn_s_setprio(0)

#define BREAD(BF, L)                                                           \
  BF[0] = *(const v4i*)(bb + ((8 + (((L) << 2) | nsub)) << 10) + lane * 16);   \
  BF[1] = *(const v4i*)(bb + ((8 + (((L) << 2) | 2 | nsub)) << 10) + lane * 16)

  int bufc = 0;
  for (int t2 = 0; t2 < NT2; ++t2) {
    if (t2 == NT2 - 1) asm volatile("s_waitcnt vmcnt(0)" ::: "memory");
    else               asm volatile("s_waitcnt vmcnt(6)" ::: "memory");
    __builtin_amdgcn_s_barrier();            // buf(t2) ready for all waves
    const int8_t* bb = sm.buf[bufc];
    int b2 = bufc + 2; if (b2 >= 3) b2 -= 3;
    const bool stage = (t2 + 2 < NT2);
    const size_t soff = (size_t)(t2 + 2) * 2048;

    v4i afr[2][2], bf0[2], bf1[2];
    // ---- P0: stage A(2); read A x4 + B(l0) x2; gate; MFMA l0
    if (stage) {
      GLOAD_LDS16(asrc[0] + soff, &sm.buf[b2][adst[0]]);
      GLOAD_LDS16(asrc[1] + soff, &sm.buf[b2][adst[1]]);
    }
#pragma unroll
    for (int mi = 0; mi < 2; ++mi)
#pragma unroll
      for (int kk = 0; kk < 2; ++kk)
        afr[mi][kk] = *(const v4i*)(bb + ((((wy * 2 + mi) << 1) | kk) << 10)
                                       + lane * 16);
    BREAD(bf0, 0);
    GATE();
    MFMA4(0, bf0);

    // ---- P1: stage B(2); read B(l1); gate; MFMA l1
    if (stage) {
      GLOAD_LDS16(bsrc[0] + soff, &sm.buf[b2][bdst[0]]);
      GLOAD_LDS16(bsrc[1] + soff, &sm.buf[b2][bdst[1]]);
    }
    BREAD(bf1, 1);
    GATE();
    MFMA4(1, bf1);

    // ---- P2: stage B(2); read B(l2); gate; MFMA l2
    if (stage) {
      GLOAD_LDS16(bsrc[2] + soff, &sm.buf[b2][bdst[2]]);
      GLOAD_LDS16(bsrc[3] + soff, &sm.buf[b2][bdst[3]]);
    }
    BREAD(bf0, 2);
    GATE();
    MFMA4(2, bf0);

    // ---- P3: read B(l3); gate; MFMA l3
    BREAD(bf1, 3);
    GATE();
    MFMA4(3, bf1);

    ++bufc; if (bufc == 3) bufc = 0;
  }
#undef BREAD
#undef MFMA4
#undef GATE

  // ---- decode D layout at runtime (uniform-byte MFMAs, permutation-immune)
  const int rep = (lane & 31) * 0x01010101;
  v4i rowv; rowv[0] = rep; rowv[1] = rep; rowv[2] = rep; rowv[3] = rep;
  v4i onev; onev[0] = 0x01010101; onev[1] = 0x01010101;
            onev[2] = 0x01010101; onev[3] = 0x01010101;
  const v16i drow = __builtin_amdgcn_mfma_i32_32x32x32_i8(rowv, onev, zero16(), 0, 0, 0);
  const v16i dcol = __builtin_amdgcn_mfma_i32_32x32x32_i8(onev, rowv, zero16(), 0, 0, 0);

  // ---- epilogue: 2 passes (mi); combine limbs, scatter f64, CLIF scan ----
  const int col = lane & 31;
  const int bl = lane >> 5;
  double* cw = sm.c[w];
#pragma unroll
  for (int mi = 0; mi < 2; ++mi) {
    __syncthreads();             // full drain; staging dead / prev pass done
#pragma unroll
    for (int i = 0; i < 16; ++i) {
      long long ts = acc[3][mi][i];
      ts = (ts << 8) + acc[2][mi][i];
      ts = (ts << 8) + acc[1][mi][i];
      ts = (ts << 8) + acc[0][mi][i];
      cw[(drow[i] >> 5) * 33 + (dcol[i] >> 5)] = (double)ts * 0x1p-36;
    }
    __syncthreads();

    const int gn = n0 + nsub * 32 + col;              // global column
    const int gm = m0 + (wy * 2 + mi) * 32 + bl * 16; // global row of t=0
    const double bj = (double)bias[gn];
    double cc = 0.0, vv = 0.0, ss = 0.0;
    if (!FINAL) {
      int8_t* so = (int8_t*)outp;                     // next layer's AF
      const size_t ab = af_addr(gm, gn);              // +t*16 per step
#pragma unroll
      for (int t = 0; t < TT; ++t) {
        const double x = cw[(bl * 16 + t) * 33 + col] + bj;
        cc = cc * 0.5 + x;                    // NEURON_CDECAY
        vv = vv * 0.75 * (1.0 - ss) + cc;     // NEURON_VDECAY, soft reset
        ss = (vv > 0.5) ? 1.0 : 0.0;          // NEURON_VTH
        so[ab + (size_t)t * 16] = (int8_t)ss;
      }
    } else {
      float tot = 0.0f;
#pragma unroll
      for (int t = 0; t < TT; ++t) {
        const double x = cw[(bl * 16 + t) * 33 + col] + bj;
        cc = cc * 0.5 + x;
        vv = vv * 0.75 * (1.0 - ss) + cc;
        ss = (vv > 0.5) ? 1.0 : 0.0;
        tot += (float)ss;
      }
      ((float*)outp)[(size_t)(gm / TT) * N + gn] = tot * 0.0625f;
    }
  }
}

extern "C" void kernel_launch(void* const* d_in, const int* in_sizes, int n_in,
                              void* d_out, int out_size, void* d_ws, size_t ws_size,
                              hipStream_t stream) {
  const float* X  = (const float*)d_in[0];  // [256][2048][16]
  const float* W0 = (const float*)d_in[1];  // [2048][2048]
  const float* b0 = (const float*)d_in[2];
  const float* W1 = (const float*)d_in[3];  // [2048][2048]
  const float* b1 = (const float*)d_in[4];
  const float* Wo = (const float*)d_in[5];  // [1024][2048]
  const float* bo = (const float*)d_in[6];
  float* out = (float*)d_out;               // [256][1024]

  int8_t* base = (int8_t*)d_ws;
  int8_t* AF0 = base;                                   // 8.39 MB
  int8_t* AF1 = base + (size_t)8388608;                 // 8.39 MB
  int8_t* AF2 = AF0;                                    // reuse after layer 0
  int8_t* F0  = base + (size_t)16777216;                // 4x4 MB = 16.8 MB
  int8_t* F1  = base + (size_t)33554432;                // 16.8 MB
  int8_t* Fo  = base + (size_t)50331648;                // 8.39 MB

  prep_limbs_all<<<2560, 256, 0, stream>>>(W0, W1, Wo, F0, F1, Fo);
  transpose_x_af<<<2048, 256, 0, stream>>>(X, AF0);

  gemm_scan_i8<2048, false><<<1024, 256, 0, stream>>>(AF0, F0, b0, AF1);
  gemm_scan_i8<2048, false><<<1024, 256, 0, stream>>>(AF1, F1, b1, AF2);
  gemm_scan_i8<1024, true ><<< 512, 256, 0, stream>>>(AF2, Fo, bo, out);
}